// Round 5
// baseline (280.001 us; speedup 1.0000x reference)
//
#include <hip/hip_runtime.h>
#include <hip/hip_bf16.h>

#define NB 4
#define NI 40000
#define DI 512
#define NH 128
#define TM 32
#define NTB 1250        // tiles per batch
#define SPB 128         // persistent blocks per batch; grid = 4*128 = 512 = 2/CU

typedef __attribute__((ext_vector_type(8))) short bf16x8;
typedef __attribute__((ext_vector_type(4))) float f32x4;

#define ASM_LGKM0()  asm volatile("s_waitcnt lgkmcnt(0)" ::: "memory")
#define SBAR()       { asm volatile("" ::: "memory"); __builtin_amdgcn_s_barrier(); asm volatile("" ::: "memory"); }

__device__ __forceinline__ ushort f2b(float f) {
    union { float f; unsigned u; } x; x.f = f;
    unsigned r = x.u + 0x7FFFu + ((x.u >> 16) & 1u);
    return (ushort)(r >> 16);
}
__device__ __forceinline__ float b2f(ushort u) {
    union { unsigned u; float f; } x; x.u = ((unsigned)u) << 16;
    return x.f;
}
__device__ __forceinline__ float tanh_fast(float x) {
    x = fminf(15.f, fmaxf(-15.f, x));
    float e = __expf(2.f * x);
    return (e - 1.f) / (e + 1.f);
}

// ---------------- weight transpose + bf16 convert ----------------
__global__ void k_wt(const float* __restrict__ w1, const float* __restrict__ w2,
                     ushort* __restrict__ w1t, ushort* __restrict__ w2t) {
    int idx = blockIdx.x * 256 + threadIdx.x;
    if (idx < 65536) {
        int j = idx >> 9, i = idx & 511;
        w1t[idx] = f2b(w1[i * 128 + j]);
    } else if (idx < 81920) {
        int r = idx - 65536;
        int j = r >> 7, k = r & 127;
        w2t[r] = f2b(w2[k * 128 + j]);
    }
}

// ---------------- argmax stage 1 ----------------
__global__ void k_am1(const float* __restrict__ c, float* __restrict__ pv, int* __restrict__ pi) {
    int blk = blockIdx.x;
    int bo = blk >> 4, ch = blk & 15;
    int b = bo >> 1, o = bo & 1;
    __shared__ float rv[256];
    __shared__ int   ri[256];
    int tid = threadIdx.x;
    float bv = -3.402823466e38f; int bi = 0x7fffffff;
    for (int n = ch * 2500 + tid; n < (ch + 1) * 2500; n += 256) {
        float v = c[((size_t)b * NI + n) * 2 + o];
        if (v > bv || (v == bv && n < bi)) { bv = v; bi = n; }
    }
    rv[tid] = bv; ri[tid] = bi;
    __syncthreads();
    for (int s = 128; s > 0; s >>= 1) {
        if (tid < s) {
            if (rv[tid + s] > rv[tid] || (rv[tid + s] == rv[tid] && ri[tid + s] < ri[tid])) {
                rv[tid] = rv[tid + s]; ri[tid] = ri[tid + s];
            }
        }
        __syncthreads();
    }
    if (tid == 0) { pv[blk] = rv[0]; pi[blk] = ri[0]; }
}

// ---------------- argmax stage 2 ----------------
__global__ void k_am2(const float* __restrict__ pv, const int* __restrict__ pi,
                      int* __restrict__ topidx) {
    int bo = blockIdx.x;
    if (threadIdx.x == 0) {
        float bv = -3.402823466e38f; int bi = 0x7fffffff;
        for (int ch = 0; ch < 16; ++ch) {
            float v = pv[bo * 16 + ch]; int idx = pi[bo * 16 + ch];
            if (v > bv || (v == bv && idx < bi)) { bv = v; bi = idx; }
        }
        topidx[bo] = bi;
    }
}

// ---------------- q_max MLP ----------------
__global__ void k_qmax(const float* __restrict__ feats, const int* __restrict__ topidx,
                       const float* __restrict__ w1, const float* __restrict__ b1,
                       const float* __restrict__ w2, const float* __restrict__ b2,
                       float* __restrict__ qmax) {
    int bo = blockIdx.x;
    int b = bo >> 1;
    __shared__ float xs[DI];
    __shared__ float hs[NH];
    int tid = threadIdx.x;               // 512
    const float* x = feats + ((size_t)b * NI + topidx[bo]) * DI;
    if (tid < DI) xs[tid] = x[tid];
    __syncthreads();
    int j = tid >> 2, part = tid & 3;
    float p = 0.f;
    for (int i = part * 128; i < part * 128 + 128; ++i)
        p += xs[i] * w1[i * NH + j];
    p += __shfl_xor(p, 1); p += __shfl_xor(p, 2);
    if (part == 0) { float h = p + b1[j]; hs[j] = h > 0.f ? h : 0.f; }
    __syncthreads();
    p = 0.f;
    for (int i = part * 32; i < part * 32 + 32; ++i)
        p += hs[i] * w2[i * NH + j];
    p += __shfl_xor(p, 1); p += __shfl_xor(p, 2);
    if (part == 0) qmax[bo * NH + j] = tanhf(p + b2[j]);
}

// ---------------- main fused kernel ----------------
// 512 blocks (2/CU), 256 threads (4 waves = 4 col-quarters), TM=32 rows/tile.
// X: reg-staged (issue loads at tile start, cvt+ds_write after softmax) into
// double-buffered bf16 LDS (16B-granule XOR swizzle). W1 streamed from L2
// (software-pipelined); W2/biases/qmax in registers. Raw barriers (no vmcnt
// drain) keep prefetch loads in flight across the whole compute phase.
__global__ __launch_bounds__(256, 2)
void k_main(const float* __restrict__ feats,
            const ushort* __restrict__ w1t, const ushort* __restrict__ w2t,
            const float* __restrict__ b1, const float* __restrict__ b2,
            const float* __restrict__ qmax,
            float* __restrict__ ews, float* __restrict__ zp, float* __restrict__ Up) {
    __shared__ __align__(16) char x_lds[2 * 32768];   // 2 x (32 rows x 1024 B bf16)
    __shared__ ushort h_lds[TM * NH];                 // 8 KB bf16, XOR-swizzled
    __shared__ float  sp_lds[4][TM][2];
    __shared__ float  e_lds[TM * 2];

    const int tid  = threadIdx.x;
    const int wn   = tid >> 6;           // wave = col quarter
    const int lane = tid & 63;
    const int sub  = blockIdx.x & (SPB - 1);
    const int b    = blockIdx.x >> 7;

    const int lr  = lane & 15;
    const int lkg = lane >> 4;           // 0..3: k-subgroup
    const int lk  = lkg * 8;
    const int l4  = lkg * 4;
    const int rsw = lr & 7;              // row-swizzle term for A reads

    // ---- per-thread constants / register-resident small weights ----
    const int col0 = wn * 32 + lr;
    const int col1 = col0 + 16;
    const float rb1_0 = b1[col0], rb1_1 = b1[col1];
    const float rb2_0 = b2[col0], rb2_1 = b2[col1];
    const float qm00 = qmax[b * 256 + col0];
    const float qm01 = qmax[b * 256 + col1];
    const float qm10 = qmax[b * 256 + NH + col0];
    const float qm11 = qmax[b * 256 + NH + col1];

    bf16x8 W2f0[4], W2f1[4];
#pragma unroll
    for (int ks = 0; ks < 4; ++ks) {
        W2f0[ks] = *(const bf16x8*)&w2t[(size_t)col0 * NH + ks * 32 + lk];
        W2f1[ks] = *(const bf16x8*)&w2t[(size_t)col1 * NH + ks * 32 + lk];
    }
    const ushort* wb0 = w1t + (size_t)col0 * DI + lk;
    const ushort* wb1 = w1t + (size_t)col1 * DI + lk;

    const int cnt = (NTB - sub + SPB - 1) / SPB;     // 9 or 10 tiles
    const float* fb = feats + (size_t)b * NI * DI;

    // persistent accumulators
    float u00 = 0.f, u01 = 0.f, u10 = 0.f, u11 = 0.f, zacc = 0.f;

    float4 pf[16];   // 64 VGPR staging (tile = 64 KB f32 / 256 thr)

    auto issue_loads = [&](int i) {
        const float4* xg4 = (const float4*)(fb + (size_t)(sub + SPB * i) * TM * DI);
#pragma unroll
        for (int q = 0; q < 16; ++q) pf[q] = xg4[tid + q * 256];
    };
    auto write_tile = [&](int bufsel) {
        char* xb = x_lds + bufsel * 32768;
#pragma unroll
        for (int q = 0; q < 16; ++q) {
            int idx = tid + q * 256;
            int row = idx >> 7, c4 = idx & 127;
            unsigned lo, hi;
            asm("v_cvt_pk_bf16_f32 %0, %1, %2" : "=v"(lo) : "v"(pf[q].x), "v"(pf[q].y));
            asm("v_cvt_pk_bf16_f32 %0, %1, %2" : "=v"(hi) : "v"(pf[q].z), "v"(pf[q].w));
            uint2 u; u.x = lo; u.y = hi;
            *(uint2*)(xb + row * 1024 + ((((c4 >> 1) ^ (row & 7)) << 4) | ((c4 & 1) * 8))) = u;
        }
    };

    // ---- prologue: tile 0 into buf 0; issue tile 1 ----
    issue_loads(0);
    write_tile(0);
    if (1 < cnt) issue_loads(1);
    ASM_LGKM0();
    SBAR();

    int cur = 0;
    for (int i = 0; i < cnt; ++i) {
        const int n0 = (sub + SPB * i) * TM;
        const char* xb = x_lds + cur * 32768;
        const char* xr0 = xb + lr * 1024;
        const char* xr1 = xb + (16 + lr) * 1024;

        // ---- layer 1: X[32,512] @ W1[512,128], W1 pipelined from L2 ----
        f32x4 acc00 = {}, acc01 = {}, acc10 = {}, acc11 = {};
        {
            bf16x8 WA0[4], WA1[4], WB0[4], WB1[4];
#pragma unroll
            for (int j = 0; j < 4; ++j) {
                WA0[j] = *(const bf16x8*)(wb0 + j * 32);
                WA1[j] = *(const bf16x8*)(wb1 + j * 32);
            }
#pragma unroll
            for (int g = 0; g < 4; ++g) {
                bf16x8* C0 = (g & 1) ? WB0 : WA0;
                bf16x8* C1 = (g & 1) ? WB1 : WA1;
                bf16x8* N0 = (g & 1) ? WA0 : WB0;
                bf16x8* N1 = (g & 1) ? WA1 : WB1;
                if (g < 3) {
#pragma unroll
                    for (int j = 0; j < 4; ++j) {
                        N0[j] = *(const bf16x8*)(wb0 + (g + 1) * 128 + j * 32);
                        N1[j] = *(const bf16x8*)(wb1 + (g + 1) * 128 + j * 32);
                    }
                }
#pragma unroll
                for (int j = 0; j < 4; ++j) {
                    int ks = g * 4 + j;
                    int off = ((ks * 4 + lkg) ^ rsw) << 4;
                    bf16x8 a0 = *(const bf16x8*)(xr0 + off);
                    bf16x8 a1 = *(const bf16x8*)(xr1 + off);
                    acc00 = __builtin_amdgcn_mfma_f32_16x16x32_bf16(a0, C0[j], acc00, 0, 0, 0);
                    acc01 = __builtin_amdgcn_mfma_f32_16x16x32_bf16(a0, C1[j], acc01, 0, 0, 0);
                    acc10 = __builtin_amdgcn_mfma_f32_16x16x32_bf16(a1, C0[j], acc10, 0, 0, 0);
                    acc11 = __builtin_amdgcn_mfma_f32_16x16x32_bf16(a1, C1[j], acc11, 0, 0, 0);
                }
            }
        }

        // ---- epilogue 1: bias + relu -> h_lds ----
#pragma unroll
        for (int r = 0; r < 4; ++r) {
            int row0 = l4 + r, row1 = 16 + l4 + r;
            float v00 = acc00[r] + rb1_0, v01 = acc01[r] + rb1_1;
            float v10 = acc10[r] + rb1_0, v11 = acc11[r] + rb1_1;
            *(ushort*)((char*)h_lds + row0 * 256 + ((col0 * 2) ^ ((row0 & 7) << 4))) = f2b(v00 > 0.f ? v00 : 0.f);
            *(ushort*)((char*)h_lds + row0 * 256 + ((col1 * 2) ^ ((row0 & 7) << 4))) = f2b(v01 > 0.f ? v01 : 0.f);
            *(ushort*)((char*)h_lds + row1 * 256 + ((col0 * 2) ^ ((row1 & 7) << 4))) = f2b(v10 > 0.f ? v10 : 0.f);
            *(ushort*)((char*)h_lds + row1 * 256 + ((col1 * 2) ^ ((row1 & 7) << 4))) = f2b(v11 > 0.f ? v11 : 0.f);
        }
        ASM_LGKM0();
        SBAR();

        // ---- layer 2: H[32,128] @ W2(regs) ----
        f32x4 c200 = {}, c201 = {}, c210 = {}, c211 = {};
        {
            const char* hr0 = (const char*)h_lds + lr * 256;
            const char* hr1 = (const char*)h_lds + (16 + lr) * 256;
            const int rsw2 = rsw << 4;
#pragma unroll
            for (int ks = 0; ks < 4; ++ks) {
                int off = (ks * 64 + lk * 2) ^ rsw2;
                bf16x8 a0 = *(const bf16x8*)(hr0 + off);
                bf16x8 a1 = *(const bf16x8*)(hr1 + off);
                c200 = __builtin_amdgcn_mfma_f32_16x16x32_bf16(a0, W2f0[ks], c200, 0, 0, 0);
                c201 = __builtin_amdgcn_mfma_f32_16x16x32_bf16(a0, W2f1[ks], c201, 0, 0, 0);
                c210 = __builtin_amdgcn_mfma_f32_16x16x32_bf16(a1, W2f0[ks], c210, 0, 0, 0);
                c211 = __builtin_amdgcn_mfma_f32_16x16x32_bf16(a1, W2f1[ks], c211, 0, 0, 0);
            }
        }

        // ---- epilogue 2: tanh + dot(qmax), 16-lane reduce -> sp_lds ----
#pragma unroll
        for (int m = 0; m < 2; ++m)
#pragma unroll
            for (int r = 0; r < 4; ++r) {
                float q0 = tanh_fast((m ? c210[r] : c200[r]) + rb2_0);
                float q1 = tanh_fast((m ? c211[r] : c201[r]) + rb2_1);
                float p0 = q0 * qm00 + q1 * qm01;
                float p1 = q0 * qm10 + q1 * qm11;
                p0 += __shfl_xor(p0, 1); p1 += __shfl_xor(p1, 1);
                p0 += __shfl_xor(p0, 2); p1 += __shfl_xor(p1, 2);
                p0 += __shfl_xor(p0, 4); p1 += __shfl_xor(p1, 4);
                p0 += __shfl_xor(p0, 8); p1 += __shfl_xor(p1, 8);
                if (lr == 0) {
                    int row = m * 16 + l4 + r;
                    sp_lds[wn][row][0] = p0;
                    sp_lds[wn][row][1] = p1;
                }
            }
        ASM_LGKM0();
        SBAR();

        // ---- s-finish (wave 0): e, global e-write, z partial ----
        if (tid < 64) {
            int row = tid >> 1, o = tid & 1;
            float s = (sp_lds[0][row][o] + sp_lds[1][row][o] +
                       sp_lds[2][row][o] + sp_lds[3][row][o]) * 0.005f;
            float e = __expf(s);
            e_lds[row * 2 + o] = e;
            ews[((size_t)(b * NI + n0 + row)) * 2 + o] = e;
            float z = e;
            z += __shfl_xor(z, 2);  z += __shfl_xor(z, 4);
            z += __shfl_xor(z, 8);  z += __shfl_xor(z, 16);
            z += __shfl_xor(z, 32);
            if (tid < 2) zacc += z;
        }
        ASM_LGKM0();
        SBAR();

        // ---- finish staging tile i+1 (loads in flight since last iter) ----
        if (i + 1 < cnt) write_tile(cur ^ 1);
        // ---- issue tile i+2 loads (span next iteration's compute) ----
        if (i + 2 < cnt) issue_loads(i + 2);

        // ---- U phase: e-weighted bf16 column sums (2 d per thread) ----
        {
            const int gsl = tid >> 2, lo4 = (tid & 3) * 4;
#pragma unroll 8
            for (int n = 0; n < TM; ++n) {
                unsigned v = *(const unsigned*)(xb + n * 1024 + (((gsl ^ (n & 7)) << 4) | lo4));
                float2 ev = *(const float2*)&e_lds[n * 2];
                float x0 = b2f((ushort)(v & 0xffff));
                float x1 = b2f((ushort)(v >> 16));
                u00 += ev.x * x0; u01 += ev.x * x1;
                u10 += ev.y * x0; u11 += ev.y * x1;
            }
        }
        ASM_LGKM0();
        SBAR();
        cur ^= 1;
    }

    // ---- block epilogue ----
    {
        size_t base = ((size_t)(b * SPB + sub) * 2) * DI;
        float2 v0; v0.x = u00; v0.y = u01;
        float2 v1; v1.x = u10; v1.y = u11;
        *(float2*)&Up[base + tid * 2] = v0;
        *(float2*)&Up[base + DI + tid * 2] = v1;
        if (tid < 2) zp[(b * SPB + sub) * 2 + tid] = zacc;
    }
}

// ---------------- Z reduce (128 partials per (b,o)) ----------------
__global__ void k_zred(const float* __restrict__ zp, float* __restrict__ Zt) {
    int bo = blockIdx.x; int b = bo >> 1, o = bo & 1;
    int tid = threadIdx.x;   // 64
    float z = zp[(b * SPB + tid) * 2 + o] + zp[(b * SPB + tid + 64) * 2 + o];
    z += __shfl_xor(z, 1);  z += __shfl_xor(z, 2);
    z += __shfl_xor(z, 4);  z += __shfl_xor(z, 8);
    z += __shfl_xor(z, 16); z += __shfl_xor(z, 32);
    if (tid == 0) Zt[bo] = z;
}

// ---------------- A output ----------------
__global__ void k_A(const float* __restrict__ ews, const float* __restrict__ Zt,
                    float* __restrict__ outA) {
    int idx = blockIdx.x * 256 + threadIdx.x;
    int b = idx / (NI * 2);
    int o = idx & 1;
    outA[idx] = ews[idx] / Zt[b * 2 + o];
}

// ---------------- B output (sum 128 partials) ----------------
__global__ void k_B(const float* __restrict__ Up, const float* __restrict__ Zt,
                    float* __restrict__ outB) {
    int bo = blockIdx.x; int d = threadIdx.x;   // 512
    int b = bo >> 1, o = bo & 1;
    float u = 0.f;
    for (int s2 = 0; s2 < SPB; ++s2)
        u += Up[(((size_t)(b * SPB + s2)) * 2 + o) * DI + d];
    outB[bo * DI + d] = u / Zt[bo];
}

// ---------------- C output ----------------
__global__ void k_C(const float* __restrict__ outB, const float* __restrict__ fcc_w,
                    const float* __restrict__ fcc_b, float* __restrict__ outC) {
    int bo = blockIdx.x; int b = bo >> 1, o = bo & 1;
    __shared__ float red[256];
    int tid = threadIdx.x;
    float acc = 0.f;
    for (int idx = tid; idx < 2 * DI; idx += 256) {
        int i = idx >> 9, d = idx & 511;
        acc += outB[(b * 2 + i) * DI + d] * fcc_w[o * (2 * DI) + i * DI + d];
    }
    red[tid] = acc; __syncthreads();
    for (int s = 128; s > 0; s >>= 1) {
        if (tid < s) red[tid] += red[tid + s];
        __syncthreads();
    }
    if (tid == 0) outC[bo] = red[0] + fcc_b[o];
}

extern "C" void kernel_launch(void* const* d_in, const int* in_sizes, int n_in,
                              void* d_out, int out_size, void* d_ws, size_t ws_size,
                              hipStream_t stream) {
    const float* feats = (const float*)d_in[0];
    const float* c     = (const float*)d_in[1];
    const float* q_w1  = (const float*)d_in[2];
    const float* q_b1  = (const float*)d_in[3];
    const float* q_w2  = (const float*)d_in[4];
    const float* q_b2  = (const float*)d_in[5];
    const float* fcc_w = (const float*)d_in[6];
    const float* fcc_b = (const float*)d_in[7];
    float* out = (float*)d_out;

    // workspace layout (bytes)
    char* w = (char*)d_ws;
    ushort* w1t  = (ushort*)(w);                 // 131072
    ushort* w2t  = (ushort*)(w + 131072);        //  32768 -> 163840
    float* qmaxb = (float*)(w + 163840);         //   4096 -> 167936
    int*   topi  = (int*)(w + 167936);           //     32 -> 167968
    float* Zt    = (float*)(w + 167968);         //     32 -> 168000
    float* pv    = (float*)(w + 168000);         //    512 -> 168512
    int*   pi    = (int*)(w + 168512);           //    512 -> 169024
    float* ews   = (float*)(w + 169024);         // 1280000 -> 1449024
    float* zp    = (float*)(w + 1449024);        //   4096 -> 1453120
    float* Up    = (float*)(w + 1453120);        // 2097152 -> 3550272

    float* outC = out;
    float* outA = out + 8;
    float* outB = out + 8 + NB * NI * 2;

    k_wt<<<320, 256, 0, stream>>>(q_w1, q_w2, w1t, w2t);
    k_am1<<<128, 256, 0, stream>>>(c, pv, pi);
    k_am2<<<8, 64, 0, stream>>>(pv, pi, topi);
    k_qmax<<<8, 512, 0, stream>>>(feats, topi, q_w1, q_b1, q_w2, q_b2, qmaxb);
    k_main<<<NB * SPB, 256, 0, stream>>>(feats, w1t, w2t, q_b1, q_b2, qmaxb, ews, zp, Up);
    k_zred<<<8, 64, 0, stream>>>(zp, Zt);
    k_A<<<NB * NI * 2 / 256, 256, 0, stream>>>(ews, Zt, outA);
    k_B<<<8, 512, 0, stream>>>(Up, Zt, outB);
    k_C<<<8, 256, 0, stream>>>(outB, fcc_w, fcc_b, outC);
}

// Round 6
// 258.879 us; speedup vs baseline: 1.0816x; 1.0816x over previous
//
#include <hip/hip_runtime.h>
#include <hip/hip_bf16.h>

#define NB 4
#define NI 40000
#define DI 512
#define NH 128
#define TM 32
#define NTB 1250        // TM=32 tiles per batch
#define SPB 128         // persistent k_mlp blocks per batch (grid 512 = 2/CU)

typedef __attribute__((ext_vector_type(8))) short bf16x8;
typedef __attribute__((ext_vector_type(4))) float f32x4;

#define GLOAD_LDS16(gp, lp)                                                     \
    __builtin_amdgcn_global_load_lds(                                           \
        (const __attribute__((address_space(1))) void*)(gp),                    \
        (__attribute__((address_space(3))) void*)(lp), 16, 0, 0)

#define ASM_VMCNT4() asm volatile("s_waitcnt vmcnt(4)" ::: "memory")
#define ASM_LGKM0()  asm volatile("s_waitcnt lgkmcnt(0)" ::: "memory")
#define SCHED0()     __builtin_amdgcn_sched_barrier(0)
#define SBAR()       { asm volatile("" ::: "memory"); __builtin_amdgcn_s_barrier(); asm volatile("" ::: "memory"); }

__device__ __forceinline__ ushort f2b(float f) {
    union { float f; unsigned u; } x; x.f = f;
    unsigned r = x.u + 0x7FFFu + ((x.u >> 16) & 1u);
    return (ushort)(r >> 16);
}
__device__ __forceinline__ float tanh_fast(float x) {
    x = fminf(15.f, fmaxf(-15.f, x));
    float e = __expf(2.f * x);
    return (e - 1.f) / (e + 1.f);
}

// ---------------- weight transpose + bf16 convert ----------------
__global__ void k_wt(const float* __restrict__ w1, const float* __restrict__ w2,
                     ushort* __restrict__ w1t, ushort* __restrict__ w2t) {
    int idx = blockIdx.x * 256 + threadIdx.x;
    if (idx < 65536) {
        int j = idx >> 9, i = idx & 511;
        w1t[idx] = f2b(w1[i * 128 + j]);
    } else if (idx < 81920) {
        int r = idx - 65536;
        int j = r >> 7, k = r & 127;
        w2t[r] = f2b(w2[k * 128 + j]);
    }
}

// ---------------- argmax stage 1 ----------------
__global__ void k_am1(const float* __restrict__ c, float* __restrict__ pv, int* __restrict__ pi) {
    int blk = blockIdx.x;
    int bo = blk >> 4, ch = blk & 15;
    int b = bo >> 1, o = bo & 1;
    __shared__ float rv[256];
    __shared__ int   ri[256];
    int tid = threadIdx.x;
    float bv = -3.402823466e38f; int bi = 0x7fffffff;
    for (int n = ch * 2500 + tid; n < (ch + 1) * 2500; n += 256) {
        float v = c[((size_t)b * NI + n) * 2 + o];
        if (v > bv || (v == bv && n < bi)) { bv = v; bi = n; }
    }
    rv[tid] = bv; ri[tid] = bi;
    __syncthreads();
    for (int s = 128; s > 0; s >>= 1) {
        if (tid < s) {
            if (rv[tid + s] > rv[tid] || (rv[tid + s] == rv[tid] && ri[tid + s] < ri[tid])) {
                rv[tid] = rv[tid + s]; ri[tid] = ri[tid + s];
            }
        }
        __syncthreads();
    }
    if (tid == 0) { pv[blk] = rv[0]; pi[blk] = ri[0]; }
}

// ---------------- q_max MLP (argmax stage-2 fused in) ----------------
__global__ void k_qmax(const float* __restrict__ feats,
                       const float* __restrict__ pv, const int* __restrict__ pi,
                       const float* __restrict__ w1, const float* __restrict__ b1,
                       const float* __restrict__ w2, const float* __restrict__ b2,
                       float* __restrict__ qmax) {
    int bo = blockIdx.x;
    int b = bo >> 1;
    __shared__ float xs[DI];
    __shared__ float hs[NH];
    __shared__ int s_idx;
    int tid = threadIdx.x;               // 512
    if (tid == 0) {
        float bv = -3.402823466e38f; int bi = 0x7fffffff;
        for (int ch = 0; ch < 16; ++ch) {
            float v = pv[bo * 16 + ch]; int idx = pi[bo * 16 + ch];
            if (v > bv || (v == bv && idx < bi)) { bv = v; bi = idx; }
        }
        s_idx = bi;
    }
    __syncthreads();
    const float* x = feats + ((size_t)b * NI + s_idx) * DI;
    if (tid < DI) xs[tid] = x[tid];
    __syncthreads();
    int j = tid >> 2, part = tid & 3;
    float p = 0.f;
    for (int i = part * 128; i < part * 128 + 128; ++i)
        p += xs[i] * w1[i * NH + j];
    p += __shfl_xor(p, 1); p += __shfl_xor(p, 2);
    if (part == 0) { float h = p + b1[j]; hs[j] = h > 0.f ? h : 0.f; }
    __syncthreads();
    p = 0.f;
    for (int i = part * 32; i < part * 32 + 32; ++i)
        p += hs[i] * w2[i * NH + j];
    p += __shfl_xor(p, 1); p += __shfl_xor(p, 2);
    if (part == 0) qmax[bo * NH + j] = tanhf(p + b2[j]);
}

// ---------------- pass 1: MLP -> e (softmax numerators) ----------------
// Persistent: 512 blocks (2/CU), 256 threads (4 waves = col-quarters).
// X staged f32 via global_load_lds into a 3-chunk ring (chunk = 32 rows x 128 k
// = 16 KB), source pre-swizzled (granule ^ (row&7)). Counted vmcnt: chunk j
// header issues DMA(j+2); W1 fragment loads are grouped BEFORE the DMA issue
// so the compiler's own W-waits (vmcnt(4)) never drain the DMA queue.
__global__ __launch_bounds__(256, 2)
void k_mlp(const float* __restrict__ feats,
           const ushort* __restrict__ w1t, const ushort* __restrict__ w2t,
           const float* __restrict__ b1, const float* __restrict__ b2,
           const float* __restrict__ qmax,
           float* __restrict__ ews, float* __restrict__ zp) {
    __shared__ __align__(16) char xch[3][16384];   // ring: [32 rows][32 granules x 16B]
    __shared__ ushort h_lds[TM * NH];              // 8 KB, XOR-swizzled
    __shared__ float  sp_lds[4][TM][2];            // 1 KB

    const int tid  = threadIdx.x;
    const int wv   = tid >> 6;
    const int lane = tid & 63;
    const int sub  = blockIdx.x & (SPB - 1);
    const int b    = blockIdx.x >> 7;

    const int lr  = lane & 15;
    const int lkg = lane >> 4;
    const int lk  = lkg * 8;
    const int l4  = lkg * 4;
    const int rsw = lr & 7;

    const int col0 = wv * 32 + lr;
    const int col1 = col0 + 16;
    const float rb1_0 = b1[col0], rb1_1 = b1[col1];
    const float rb2_0 = b2[col0], rb2_1 = b2[col1];
    const float qm00 = qmax[b * 256 + col0];
    const float qm01 = qmax[b * 256 + col1];
    const float qm10 = qmax[b * 256 + NH + col0];
    const float qm11 = qmax[b * 256 + NH + col1];

    bf16x8 W2f0[4], W2f1[4];
#pragma unroll
    for (int ks = 0; ks < 4; ++ks) {
        W2f0[ks] = *(const bf16x8*)&w2t[(size_t)col0 * NH + ks * 32 + lk];
        W2f1[ks] = *(const bf16x8*)&w2t[(size_t)col1 * NH + ks * 32 + lk];
    }

    const float* fb = feats + (size_t)b * NI * DI;
    const int ntile  = (NTB - sub + SPB - 1) / SPB;   // 9 or 10
    const int nchunk = ntile * 4;

    float zacc = 0.f;

    // DMA one chunk (global chunk index cc): wave stages rows 8wv..8wv+7.
    auto issue_dma = [&](int cc2) {
        int t = sub + (cc2 >> 2) * SPB;
        int c = cc2 & 3;
        char* base = xch[cc2 % 3] + wv * 4096;
        const char* srow = (const char*)fb + (size_t)t * TM * 2048 + c * 512;
#pragma unroll
        for (int q = 0; q < 4; ++q) {
            int r  = wv * 8 + q * 2 + (lane >> 5);
            int gs = (lane & 31) ^ (r & 7);
            GLOAD_LDS16(srow + (size_t)r * 2048 + gs * 16, base + q * 1024);
        }
    };

    // prologue: chunks 0 and 1 in flight
    issue_dma(0);
    issue_dma(1);

    int cc = 0;
    for (int ti = 0; ti < ntile; ++ti) {
        const int t  = sub + ti * SPB;
        const int n0 = t * TM;

        f32x4 acc00 = {}, acc01 = {}, acc10 = {}, acc11 = {};

        for (int c = 0; c < 4; ++c, ++cc) {
            ASM_VMCNT4();          // own DMA slice of chunk cc landed
            SCHED0();
            SBAR();                // all waves' slices landed; buf((cc+2)%3) free
            SCHED0();

            // W1 fragments for this chunk (grouped BEFORE DMA issue)
            bf16x8 Wa[4], Wb[4];
#pragma unroll
            for (int k4 = 0; k4 < 4; ++k4) {
                int kk = (c * 4 + k4) * 32 + lk;
                Wa[k4] = *(const bf16x8*)&w1t[(size_t)col0 * DI + kk];
                Wb[k4] = *(const bf16x8*)&w1t[(size_t)col1 * DI + kk];
            }
            SCHED0();
            if (cc + 2 < nchunk) issue_dma(cc + 2);
            SCHED0();

            const char* xb = xch[cc % 3];
            const char* xr0 = xb + lr * 512;
            const char* xr1 = xb + (16 + lr) * 512;
#pragma unroll
            for (int k4 = 0; k4 < 4; ++k4) {
                int gs = k4 * 8 + lkg * 2;
                float4 a00 = *(const float4*)(xr0 + ((gs ^ rsw) << 4));
                float4 a01 = *(const float4*)(xr0 + (((gs + 1) ^ rsw) << 4));
                float4 a10 = *(const float4*)(xr1 + ((gs ^ rsw) << 4));
                float4 a11 = *(const float4*)(xr1 + (((gs + 1) ^ rsw) << 4));
                unsigned p0, p1, p2, p3, p4, p5, p6, p7;
                asm("v_cvt_pk_bf16_f32 %0, %1, %2" : "=v"(p0) : "v"(a00.x), "v"(a00.y));
                asm("v_cvt_pk_bf16_f32 %0, %1, %2" : "=v"(p1) : "v"(a00.z), "v"(a00.w));
                asm("v_cvt_pk_bf16_f32 %0, %1, %2" : "=v"(p2) : "v"(a01.x), "v"(a01.y));
                asm("v_cvt_pk_bf16_f32 %0, %1, %2" : "=v"(p3) : "v"(a01.z), "v"(a01.w));
                asm("v_cvt_pk_bf16_f32 %0, %1, %2" : "=v"(p4) : "v"(a10.x), "v"(a10.y));
                asm("v_cvt_pk_bf16_f32 %0, %1, %2" : "=v"(p5) : "v"(a10.z), "v"(a10.w));
                asm("v_cvt_pk_bf16_f32 %0, %1, %2" : "=v"(p6) : "v"(a11.x), "v"(a11.y));
                asm("v_cvt_pk_bf16_f32 %0, %1, %2" : "=v"(p7) : "v"(a11.z), "v"(a11.w));
                union { unsigned u[4]; bf16x8 v; } A0, A1;
                A0.u[0] = p0; A0.u[1] = p1; A0.u[2] = p2; A0.u[3] = p3;
                A1.u[0] = p4; A1.u[1] = p5; A1.u[2] = p6; A1.u[3] = p7;
                acc00 = __builtin_amdgcn_mfma_f32_16x16x32_bf16(A0.v, Wa[k4], acc00, 0, 0, 0);
                acc01 = __builtin_amdgcn_mfma_f32_16x16x32_bf16(A0.v, Wb[k4], acc01, 0, 0, 0);
                acc10 = __builtin_amdgcn_mfma_f32_16x16x32_bf16(A1.v, Wa[k4], acc10, 0, 0, 0);
                acc11 = __builtin_amdgcn_mfma_f32_16x16x32_bf16(A1.v, Wb[k4], acc11, 0, 0, 0);
            }
        }

        // ---- epilogue 1: bias + relu -> h_lds ----
#pragma unroll
        for (int r = 0; r < 4; ++r) {
            int row0 = l4 + r, row1 = 16 + l4 + r;
            float v00 = acc00[r] + rb1_0, v01 = acc01[r] + rb1_1;
            float v10 = acc10[r] + rb1_0, v11 = acc11[r] + rb1_1;
            *(ushort*)((char*)h_lds + row0 * 256 + ((col0 * 2) ^ ((row0 & 7) << 4))) = f2b(v00 > 0.f ? v00 : 0.f);
            *(ushort*)((char*)h_lds + row0 * 256 + ((col1 * 2) ^ ((row0 & 7) << 4))) = f2b(v01 > 0.f ? v01 : 0.f);
            *(ushort*)((char*)h_lds + row1 * 256 + ((col0 * 2) ^ ((row1 & 7) << 4))) = f2b(v10 > 0.f ? v10 : 0.f);
            *(ushort*)((char*)h_lds + row1 * 256 + ((col1 * 2) ^ ((row1 & 7) << 4))) = f2b(v11 > 0.f ? v11 : 0.f);
        }
        ASM_LGKM0();
        SBAR();

        // ---- layer 2: H[32,128] @ W2(regs) ----
        f32x4 c200 = {}, c201 = {}, c210 = {}, c211 = {};
        {
            const char* hr0 = (const char*)h_lds + lr * 256;
            const char* hr1 = (const char*)h_lds + (16 + lr) * 256;
            const int rsw2 = rsw << 4;
#pragma unroll
            for (int ks = 0; ks < 4; ++ks) {
                int off = (ks * 64 + lk * 2) ^ rsw2;
                bf16x8 a0 = *(const bf16x8*)(hr0 + off);
                bf16x8 a1 = *(const bf16x8*)(hr1 + off);
                c200 = __builtin_amdgcn_mfma_f32_16x16x32_bf16(a0, W2f0[ks], c200, 0, 0, 0);
                c201 = __builtin_amdgcn_mfma_f32_16x16x32_bf16(a0, W2f1[ks], c201, 0, 0, 0);
                c210 = __builtin_amdgcn_mfma_f32_16x16x32_bf16(a1, W2f0[ks], c210, 0, 0, 0);
                c211 = __builtin_amdgcn_mfma_f32_16x16x32_bf16(a1, W2f1[ks], c211, 0, 0, 0);
            }
        }

        // ---- epilogue 2: tanh + dot(qmax), 16-lane reduce -> sp_lds ----
#pragma unroll
        for (int m = 0; m < 2; ++m)
#pragma unroll
            for (int r = 0; r < 4; ++r) {
                float q0 = tanh_fast((m ? c210[r] : c200[r]) + rb2_0);
                float q1 = tanh_fast((m ? c211[r] : c201[r]) + rb2_1);
                float p0 = q0 * qm00 + q1 * qm01;
                float p1 = q0 * qm10 + q1 * qm11;
                p0 += __shfl_xor(p0, 1); p1 += __shfl_xor(p1, 1);
                p0 += __shfl_xor(p0, 2); p1 += __shfl_xor(p1, 2);
                p0 += __shfl_xor(p0, 4); p1 += __shfl_xor(p1, 4);
                p0 += __shfl_xor(p0, 8); p1 += __shfl_xor(p1, 8);
                if (lr == 0) {
                    int row = m * 16 + l4 + r;
                    sp_lds[wv][row][0] = p0;
                    sp_lds[wv][row][1] = p1;
                }
            }
        ASM_LGKM0();
        SBAR();

        // ---- s-finish (wave 0): e, global e-write, z partial ----
        if (tid < 64) {
            int row = tid >> 1, o = tid & 1;
            float s = (sp_lds[0][row][o] + sp_lds[1][row][o] +
                       sp_lds[2][row][o] + sp_lds[3][row][o]) * 0.005f;
            float e = __expf(s);
            ews[(size_t)(b * NI + n0) * 2 + tid] = e;
            float z = e;
            z += __shfl_xor(z, 2);  z += __shfl_xor(z, 4);
            z += __shfl_xor(z, 8);  z += __shfl_xor(z, 16);
            z += __shfl_xor(z, 32);
            if (tid < 2) zacc += z;
        }
        ASM_LGKM0();
        SBAR();      // sp_lds/h_lds free for next tile
    }

    if (tid < 2) zp[(b * SPB + sub) * 2 + tid] = zacc;
}

// ---------------- Z reduce (128 partials per (b,o)) ----------------
__global__ void k_zred(const float* __restrict__ zp, float* __restrict__ Zt) {
    int bo = blockIdx.x; int b = bo >> 1, o = bo & 1;
    int tid = threadIdx.x;   // 64
    float z = zp[(b * SPB + tid) * 2 + o] + zp[(b * SPB + tid + 64) * 2 + o];
    z += __shfl_xor(z, 1);  z += __shfl_xor(z, 2);
    z += __shfl_xor(z, 4);  z += __shfl_xor(z, 8);
    z += __shfl_xor(z, 16); z += __shfl_xor(z, 32);
    if (tid == 0) Zt[bo] = z;
}

// ---------------- A output ----------------
__global__ void k_A(const float* __restrict__ ews, const float* __restrict__ Zt,
                    float* __restrict__ outA) {
    int idx = blockIdx.x * 256 + threadIdx.x;
    int b = idx / (NI * 2);
    int o = idx & 1;
    outA[idx] = ews[idx] / Zt[b * 2 + o];
}

// ---------------- pass 2: U = sum e*x (streaming, reverse tile order) ----------------
// 2048 blocks (8/CU), 256 threads. Block (b, j): tiles (624-j), (624-j-512) of
// 64 rows; thread owns float4 d-slice; rh row-interleave; per-tile e in LDS.
__global__ __launch_bounds__(256)
void k_U(const float* __restrict__ feats, const float* __restrict__ ews,
         float* __restrict__ Up) {
    __shared__ float e_lds[128];
    __shared__ float u_lds[2][128][2][4];   // [rh][d4][o][4] = 8 KB

    const int tid = threadIdx.x;
    const int b = blockIdx.x >> 9;
    const int j = blockIdx.x & 511;
    const int rh = tid >> 7;
    const int d4 = tid & 127;

    const float* fb = feats + (size_t)b * NI * DI;

    float4 u0 = {0.f, 0.f, 0.f, 0.f};
    float4 u1 = {0.f, 0.f, 0.f, 0.f};

    for (int tt = j; tt < 625; tt += 512) {
        const int t = 624 - tt;          // reverse: hit L3-resident tail first
        const int n0 = t * 64;
        if (tid < 128) e_lds[tid] = ews[(size_t)(b * NI + n0) * 2 + tid];
        __syncthreads();
#pragma unroll 4
        for (int r = rh; r < 64; r += 2) {
            float4 x = *(const float4*)&fb[(size_t)(n0 + r) * DI + d4 * 4];
            float e0 = e_lds[r * 2], e1 = e_lds[r * 2 + 1];
            u0.x += e0 * x.x; u0.y += e0 * x.y; u0.z += e0 * x.z; u0.w += e0 * x.w;
            u1.x += e1 * x.x; u1.y += e1 * x.y; u1.z += e1 * x.z; u1.w += e1 * x.w;
        }
        __syncthreads();
    }

    *(float4*)&u_lds[rh][d4][0][0] = u0;
    *(float4*)&u_lds[rh][d4][1][0] = u1;
    __syncthreads();
    if (tid < 128) {
#pragma unroll
        for (int o = 0; o < 2; ++o) {
            float4 a = *(const float4*)&u_lds[0][tid][o][0];
            float4 bb = *(const float4*)&u_lds[1][tid][o][0];
            float4 s; s.x = a.x + bb.x; s.y = a.y + bb.y; s.z = a.z + bb.z; s.w = a.w + bb.w;
            *(float4*)&Up[(((size_t)(b * 512 + j) * 2 + o) * DI) + tid * 4] = s;
        }
    }
}

// ---------------- B reduce: 64 blocks = (bo, 64-d chunk) ----------------
__global__ void k_B(const float* __restrict__ Up, const float* __restrict__ Zt,
                    float* __restrict__ outB) {
    __shared__ float r_lds[4][64];
    const int bo = blockIdx.x >> 3, ch = blockIdx.x & 7;
    const int b = bo >> 1, o = bo & 1;
    const int tid = threadIdx.x;          // 256
    const int pg = tid >> 6, dl = tid & 63;
    const int d = ch * 64 + dl;
    float u = 0.f;
    for (int j = pg; j < 512; j += 4)
        u += Up[((size_t)(b * 512 + j) * 2 + o) * DI + d];
    r_lds[pg][dl] = u;
    __syncthreads();
    if (tid < 64)
        outB[bo * DI + d] = (r_lds[0][dl] + r_lds[1][dl] + r_lds[2][dl] + r_lds[3][dl]) / Zt[bo];
}

// ---------------- C output ----------------
__global__ void k_C(const float* __restrict__ outB, const float* __restrict__ fcc_w,
                    const float* __restrict__ fcc_b, float* __restrict__ outC) {
    int bo = blockIdx.x; int b = bo >> 1, o = bo & 1;
    __shared__ float red[256];
    int tid = threadIdx.x;
    float acc = 0.f;
    for (int idx = tid; idx < 2 * DI; idx += 256) {
        int i = idx >> 9, d = idx & 511;
        acc += outB[(b * 2 + i) * DI + d] * fcc_w[o * (2 * DI) + i * DI + d];
    }
    red[tid] = acc; __syncthreads();
    for (int s = 128; s > 0; s >>= 1) {
        if (tid < s) red[tid] += red[tid + s];
        __syncthreads();
    }
    if (tid == 0) outC[bo] = red[0] + fcc_b[o];
}

extern "C" void kernel_launch(void* const* d_in, const int* in_sizes, int n_in,
                              void* d_out, int out_size, void* d_ws, size_t ws_size,
                              hipStream_t stream) {
    const float* feats = (const float*)d_in[0];
    const float* c     = (const float*)d_in[1];
    const float* q_w1  = (const float*)d_in[2];
    const float* q_b1  = (const float*)d_in[3];
    const float* q_w2  = (const float*)d_in[4];
    const float* q_b2  = (const float*)d_in[5];
    const float* fcc_w = (const float*)d_in[6];
    const float* fcc_b = (const float*)d_in[7];
    float* out = (float*)d_out;

    // workspace layout (bytes)
    char* w = (char*)d_ws;
    ushort* w1t  = (ushort*)(w);                 // 131072
    ushort* w2t  = (ushort*)(w + 131072);        //  32768 -> 163840
    float* qmaxb = (float*)(w + 163840);         //   4096 -> 167936
    float* Zt    = (float*)(w + 167968);         //     32 -> 168000
    float* pv    = (float*)(w + 168000);         //    512 -> 168512
    int*   pi    = (int*)(w + 168512);           //    512 -> 169024
    float* ews   = (float*)(w + 169024);         // 1280000 -> 1449024
    float* zp    = (float*)(w + 1449024);        //   4096 -> 1453120
    float* Up    = (float*)(w + 1453120);        // 8388608 -> 9841728

    float* outC = out;
    float* outA = out + 8;
    float* outB = out + 8 + NB * NI * 2;

    k_wt<<<320, 256, 0, stream>>>(q_w1, q_w2, w1t, w2t);
    k_am1<<<128, 256, 0, stream>>>(c, pv, pi);
    k_qmax<<<8, 512, 0, stream>>>(feats, pv, pi, q_w1, q_b1, q_w2, q_b2, qmaxb);
    k_mlp<<<NB * SPB, 256, 0, stream>>>(feats, w1t, w2t, q_b1, q_b2, qmaxb, ews, zp);
    k_zred<<<8, 64, 0, stream>>>(zp, Zt);
    k_A<<<NB * NI * 2 / 256, 256, 0, stream>>>(ews, Zt, outA);
    k_U<<<NB * 512, 256, 0, stream>>>(feats, ews, Up);
    k_B<<<64, 256, 0, stream>>>(Up, Zt, outB);
    k_C<<<8, 256, 0, stream>>>(outB, fcc_w, fcc_b, outC);
}